// Round 8
// baseline (61.225 us; speedup 1.0000x reference)
//
#include <hip/hip_runtime.h>
#include <math.h>

#define BB 4
#define TT 2048
#define DM 768
#define HD 64
#define NROW (BB*TT)   // 8192
#define WFRAG_HALF ((size_t)24*12*512)   // 147456 elems per part (hi | lo)

typedef __attribute__((ext_vector_type(8))) short bf16x8;
typedef __attribute__((ext_vector_type(4))) float f32x4;

__device__ __forceinline__ unsigned short f2bf(float f) {
    unsigned int u = __float_as_uint(f);
    u += 0x7FFFu + ((u >> 16) & 1u);   // RNE
    return (unsigned short)(u >> 16);
}
__device__ __forceinline__ float bf2f(unsigned short h) {
    return __uint_as_float(((unsigned int)h) << 16);
}

// -------- W -> fragment-ordered bf16 hi/lo, layout [kc(24)][nt(12)][512] --------
__global__ __launch_bounds__(256) void wconv_kernel(
    const float* __restrict__ Wq, const float* __restrict__ Wk,
    const float* __restrict__ Wv, unsigned short* __restrict__ wfrag)
{
    __shared__ float ws[32][69];
    const int blk = blockIdx.x;          // 0..71 = m*24 + kc
    const int m = blk / 24, kc = blk % 24;
    const float* Wm = (m == 0) ? Wq : ((m == 1) ? Wk : Wv);
    const float sc = (m == 0) ? 0.125f : 1.0f;
    const int tid = threadIdx.x;
    {
        int r = tid >> 3, c0 = (tid & 7) * 8;
        *(float4*)&ws[r][c0]     = *(const float4*)(Wm + (size_t)(32*kc + r)*HD + c0);
        *(float4*)&ws[r][c0 + 4] = *(const float4*)(Wm + (size_t)(32*kc + r)*HD + c0 + 4);
    }
    __syncthreads();
    const int ntm = tid >> 6, lane = tid & 63;
    const int q15 = lane & 15, g = lane >> 4;
    const int col = 16*ntm + q15;
    bf16x8 hi, lo;
    #pragma unroll
    for (int j = 0; j < 8; ++j) {
        float w = ws[8*g + j][col] * sc;
        unsigned short h = f2bf(w);
        hi[j] = (short)h;
        lo[j] = (short)f2bf(w - bf2f(h));
    }
    size_t base = ((size_t)(kc*12 + m*4 + ntm))*512 + (size_t)lane*8;
    *(bf16x8*)(wfrag + base) = hi;
    *(bf16x8*)(wfrag + WFRAG_HALF + base) = lo;
}

// -------- QKV projection: high-TLP, LDS-free K-loop --------
// grid 768 = 256 M-tiles x 3 N-blocks (nb==m: 0=q,1=k,2=v). 256 thr, 4 waves.
// Wave w: mt = w&1 (16-row half), np = w>>1; covers nt = nb*4 + 2*np + {0,1}.
__global__ __launch_bounds__(256, 3) void proj_mfma_kernel(
    const float* __restrict__ x, const unsigned short* __restrict__ wfrag,
    const float* __restrict__ bq, const float* __restrict__ bk,
    const float* __restrict__ bv,
    unsigned short* __restrict__ qo, unsigned short* __restrict__ ko,
    unsigned short* __restrict__ vT)
{
    __shared__ unsigned short stg[2304];   // qk: [32][68]; v: [64][36]
    const int tid  = threadIdx.x;
    const int wv   = tid >> 6;
    const int lane = tid & 63;
    const int q15  = lane & 15;
    const int g    = lane >> 4;
    const int bx   = blockIdx.x;
    const int nb   = bx % 3;
    const int row0 = (bx / 3) * 32;
    const int mt   = wv & 1;
    const int np   = wv >> 1;
    const int ntg0 = nb*4 + 2*np;

    const float* xp = x + (size_t)(row0 + 16*mt + q15)*DM + 8*g;

    f32x4 acc[2];
    acc[0] = (f32x4){0.f, 0.f, 0.f, 0.f};
    acc[1] = (f32x4){0.f, 0.f, 0.f, 0.f};

    for (int kcg = 0; kcg < 24; ++kcg) {
        float4 xa = *(const float4*)(xp + 32*kcg);
        float4 xb = *(const float4*)(xp + 32*kcg + 4);
        // truncation hi/lo split (err <= 2^-16 rel; xl*wl term dropped downstream)
        bf16x8 xfh, xfl;
        float f[8] = {xa.x, xa.y, xa.z, xa.w, xb.x, xb.y, xb.z, xb.w};
        #pragma unroll
        for (int e = 0; e < 8; ++e) {
            unsigned short h = (unsigned short)(__float_as_uint(f[e]) >> 16);
            float r = f[e] - bf2f(h);
            xfh[e] = (short)h;
            xfl[e] = (short)(unsigned short)(__float_as_uint(r) >> 16);
        }
        #pragma unroll
        for (int i = 0; i < 2; ++i) {
            const unsigned short* wp = wfrag + ((size_t)(kcg*12 + ntg0 + i))*512 + (size_t)lane*8;
            bf16x8 wh = *(const bf16x8*)wp;
            bf16x8 wl = *(const bf16x8*)(wp + WFRAG_HALF);
            acc[i] = __builtin_amdgcn_mfma_f32_16x16x32_bf16(xfh, wh, acc[i], 0, 0, 0);
            acc[i] = __builtin_amdgcn_mfma_f32_16x16x32_bf16(xfl, wh, acc[i], 0, 0, 0);
            acc[i] = __builtin_amdgcn_mfma_f32_16x16x32_bf16(xfh, wl, acc[i], 0, 0, 0);
        }
    }

    // ---- epilogue: LDS bounce -> coalesced stores ----
    if (nb < 2) {
        const float* bp = (nb == 0) ? bq : bk;
        const float bsc = (nb == 0) ? 0.125f : 1.0f;
        #pragma unroll
        for (int i = 0; i < 2; ++i) {
            int col = 16*(2*np + i) + q15;
            float bb = bsc * bp[col];
            #pragma unroll
            for (int r = 0; r < 4; ++r)
                stg[(size_t)(16*mt + 4*g + r)*68 + col] = f2bf(acc[i][r] + bb);
        }
        __syncthreads();
        const int rr = tid >> 3;
        const int c8 = (tid & 7) * 8;
        ushort4 a  = *(const ushort4*)&stg[(size_t)rr*68 + c8];
        ushort4 b2 = *(const ushort4*)&stg[(size_t)rr*68 + c8 + 4];
        unsigned short* op = (nb == 0) ? qo : ko;
        *(ushort4*)(op + (size_t)(row0 + rr)*HD + c8)     = a;
        *(ushort4*)(op + (size_t)(row0 + rr)*HD + c8 + 4) = b2;
    } else {
        #pragma unroll
        for (int i = 0; i < 2; ++i) {
            int h = 16*(2*np + i) + q15;
            float bb = bv[h];
            ushort4 v4;
            v4.x = f2bf(acc[i][0] + bb);
            v4.y = f2bf(acc[i][1] + bb);
            v4.z = f2bf(acc[i][2] + bb);
            v4.w = f2bf(acc[i][3] + bb);
            *(ushort4*)&stg[(size_t)h*36 + 16*mt + 4*g] = v4;
        }
        __syncthreads();
        const int h  = tid >> 2;
        const int tg = (tid & 3) * 8;
        const int b  = row0 >> 11;
        const int t0 = row0 & 2047;
        ushort4 a  = *(const ushort4*)&stg[(size_t)h*36 + tg];
        ushort4 b2 = *(const ushort4*)&stg[(size_t)h*36 + tg + 4];
        *(ushort4*)(vT + ((size_t)b*HD + h)*TT + t0 + tg)     = a;
        *(ushort4*)(vT + ((size_t)b*HD + h)*TT + t0 + tg + 4) = b2;
    }
}

// -------- Flash attention: bf16 MFMA, in-block 4-way key split (unchanged) --------
__global__ __launch_bounds__(256) void attn_mfma_kernel(
    const unsigned short* __restrict__ qb_, const unsigned short* __restrict__ kb_,
    const unsigned short* __restrict__ vt_, float* __restrict__ out)
{
    __shared__ unsigned short plds[4][16][40];
    __shared__ float olds[4][16][66];
    __shared__ float mlds[4][16][2];

    const int tid  = threadIdx.x;
    const int wv   = tid >> 6;
    const int lane = tid & 63;
    const int q15  = lane & 15;
    const int g    = lane >> 4;

    const int bx = blockIdx.x;
    const int b  = bx & 3;
    const int qt = (TT/16 - 1) - (bx >> 2);
    const int qbase = qt * 16;
    const int nk = qbase + 16;

    const unsigned short* qp = qb_ + (size_t)b*TT*HD;
    const unsigned short* kp = kb_ + (size_t)b*TT*HD;
    const unsigned short* vp = vt_ + (size_t)b*HD*TT;

    bf16x8 qf[2];
    #pragma unroll
    for (int c = 0; c < 2; ++c)
        qf[c] = *(const bf16x8*)(qp + (size_t)(qbase + q15)*HD + 32*c + 8*g);

    f32x4 accv[4];
    #pragma unroll
    for (int h = 0; h < 4; ++h) accv[h] = (f32x4){0.f, 0.f, 0.f, 0.f};
    float m = -INFINITY, l = 0.f;

    const int ck = ((nk + 127) >> 7) << 5;
    const int kstart = wv * ck;
    const int kend = min(kstart + ck, nk);

    for (int k0 = kstart; k0 < kend; k0 += 32) {
        bf16x8 vf[4];
        #pragma unroll
        for (int h = 0; h < 4; ++h)
            vf[h] = *(const bf16x8*)(vp + (size_t)(16*h + q15)*TT + k0 + 8*g);
        bf16x8 kf[2][2];
        #pragma unroll
        for (int t = 0; t < 2; ++t)
            #pragma unroll
            for (int c = 0; c < 2; ++c)
                kf[t][c] = *(const bf16x8*)(kp + (size_t)(k0 + 16*t + q15)*HD + 32*c + 8*g);

        f32x4 st[2];
        #pragma unroll
        for (int t = 0; t < 2; ++t) {
            f32x4 z = {0.f, 0.f, 0.f, 0.f};
            st[t] = __builtin_amdgcn_mfma_f32_16x16x32_bf16(kf[t][0], qf[0], z, 0, 0, 0);
            st[t] = __builtin_amdgcn_mfma_f32_16x16x32_bf16(kf[t][1], qf[1], st[t], 0, 0, 0);
        }
        if (k0 + 31 > qbase) {
            int qabs = qbase + q15;
            #pragma unroll
            for (int t = 0; t < 2; ++t)
                #pragma unroll
                for (int r = 0; r < 4; ++r)
                    if (k0 + 16*t + 4*g + r > qabs) st[t][r] = -INFINITY;
        }
        float pmax = st[0][0];
        #pragma unroll
        for (int t = 0; t < 2; ++t)
            #pragma unroll
            for (int r = 0; r < 4; ++r) pmax = fmaxf(pmax, st[t][r]);
        pmax = fmaxf(pmax, __shfl_xor(pmax, 16));
        pmax = fmaxf(pmax, __shfl_xor(pmax, 32));
        float mnew = fmaxf(m, pmax);
        float mc = fmaxf(mnew, -1e30f);
        float alpha = __expf(m - mc);
        float p[2][4];
        float psum = 0.f;
        #pragma unroll
        for (int t = 0; t < 2; ++t)
            #pragma unroll
            for (int r = 0; r < 4; ++r) {
                p[t][r] = __expf(st[t][r] - mc);
                psum += p[t][r];
            }
        psum += __shfl_xor(psum, 16);
        psum += __shfl_xor(psum, 32);
        l = l * alpha + psum;
        m = mnew;
        float av[4];
        #pragma unroll
        for (int r = 0; r < 4; ++r) av[r] = __shfl(alpha, 4*g + r);
        #pragma unroll
        for (int h = 0; h < 4; ++h)
            #pragma unroll
            for (int r = 0; r < 4; ++r) accv[h][r] *= av[r];
        #pragma unroll
        for (int t = 0; t < 2; ++t) {
            ushort4 pk;
            pk.x = f2bf(p[t][0]); pk.y = f2bf(p[t][1]);
            pk.z = f2bf(p[t][2]); pk.w = f2bf(p[t][3]);
            *(ushort4*)&plds[wv][q15][16*t + 4*g] = pk;
        }
        bf16x8 pa = *(const bf16x8*)&plds[wv][q15][8*g];
        #pragma unroll
        for (int h = 0; h < 4; ++h)
            accv[h] = __builtin_amdgcn_mfma_f32_16x16x32_bf16(pa, vf[h], accv[h], 0, 0, 0);
    }

    #pragma unroll
    for (int h = 0; h < 4; ++h)
        #pragma unroll
        for (int r = 0; r < 4; ++r)
            olds[wv][4*g + r][16*h + q15] = accv[h][r];
    if (g == 0) { mlds[wv][q15][0] = m; mlds[wv][q15][1] = l; }
    __syncthreads();

    {
        int qq = tid >> 4;
        int c4 = (tid & 15) << 2;
        float mw[4], lw[4];
        #pragma unroll
        for (int w = 0; w < 4; ++w) { mw[w] = mlds[w][qq][0]; lw[w] = mlds[w][qq][1]; }
        float M = fmaxf(fmaxf(mw[0], mw[1]), fmaxf(mw[2], mw[3]));
        float Mc = fmaxf(M, -1e30f);
        float ww[4], ltot = 0.f;
        #pragma unroll
        for (int w = 0; w < 4; ++w) { ww[w] = __expf(mw[w] - Mc); ltot += ww[w]*lw[w]; }
        float invl = 1.f / ltot;
        float4 o;
        #pragma unroll
        for (int e = 0; e < 4; ++e) {
            float s = 0.f;
            #pragma unroll
            for (int w = 0; w < 4; ++w) s += ww[w] * olds[w][qq][c4 + e];
            ((float*)&o)[e] = s * invl;
        }
        *(float4*)(out + ((size_t)b*TT + qbase + qq)*HD + c4) = o;
    }
}

extern "C" void kernel_launch(void* const* d_in, const int* in_sizes, int n_in,
                              void* d_out, int out_size, void* d_ws, size_t ws_size,
                              hipStream_t stream) {
    const float* x  = (const float*)d_in[0];
    const float* Wq = (const float*)d_in[1];
    const float* bq = (const float*)d_in[2];
    const float* Wk = (const float*)d_in[3];
    const float* bk = (const float*)d_in[4];
    const float* Wv = (const float*)d_in[5];
    const float* bv = (const float*)d_in[6];
    float* out = (float*)d_out;

    unsigned short* qbf   = (unsigned short*)d_ws;
    unsigned short* kbf   = qbf + (size_t)NROW*HD;
    unsigned short* vT    = kbf + (size_t)NROW*HD;
    unsigned short* wfrag = vT  + (size_t)NROW*HD;   // 2*147456 elems = 576KB

    wconv_kernel<<<72, 256, 0, stream>>>(Wq, Wk, Wv, wfrag);
    proj_mfma_kernel<<<768, 256, 0, stream>>>(x, wfrag, bq, bk, bv, qbf, kbf, vT);
    attn_mfma_kernel<<<dim3(TT/16 * BB), 256, 0, stream>>>(qbf, kbf, vT, out);
}